// Round 5
// baseline (49.554 us; speedup 1.0000x reference)
//
#include <hip/hip_runtime.h>

// Unfolder: out[b,c,p,q] = x[b,c, p/3 + p%3 - 1, q/3 + q%3 - 1], zero outside.
// B=8, C=3, H=W=512, k=3, pad=1 -> out is [8,3,1536,1536] fp32.
//
// Tile RG=8 row-groups per block: block m covers output rows p=24m..24m+23,
// staging input rows s = 8m-1 .. 8m+8 (10 rows, 20 KB LDS) once. This cuts
// logical HBM fetch from 3 rows/group (72 MB) to 10 rows/8 groups (30 MB),
// independent of block->XCD mapping. Stores: coalesced nontemporal float4.

#define B_N 8
#define C_N 3
#define H_N 512
#define W_N 512
#define HO 1536
#define WO 1536
#define RG 8            // row-groups per block
#define NR (RG + 2)     // staged input rows per block

typedef float fvec4 __attribute__((ext_vector_type(4)));

__global__ __launch_bounds__(384) void unfold_tile_kernel(
    const float* __restrict__ x, float* __restrict__ out)
{
    const int m   = blockIdx.x;   // row tile [0, 512/RG)
    const int bc  = blockIdx.y;   // fused batch*channel [0,24)
    const int tid = threadIdx.x;  // [0,384)

    __shared__ float rows[NR][W_N];

    // Stage NR rows: NR*128 float4, coalesced, zero-filled at borders.
    const int s0 = RG * m - 1;
    for (int idx = tid; idx < NR * (W_N / 4); idx += 384) {
        const int r  = idx >> 7;        // staged row [0,NR)
        const int cc = idx & 127;       // float4 within row
        const int s  = s0 + r;
        fvec4 v = (fvec4)0.f;
        if ((unsigned)s < (unsigned)H_N) {
            v = reinterpret_cast<const fvec4*>(
                    x + ((size_t)bc * H_N + s) * W_N)[cc];
        }
        reinterpret_cast<fvec4*>(&rows[r][0])[cc] = v;
    }
    __syncthreads();

    // Column gather indices: q = 4*tid + e, t = q/3 + q%3 - 1 in [-1,512].
    int tcol[4];
#pragma unroll
    for (int e = 0; e < 4; ++e) {
        const int q = tid * 4 + e;
        tcol[e] = q / 3 + q % 3 - 1;
    }

    // 24 output rows; row d uses staged row r = d/3 + d%3.
    const size_t obase = ((size_t)bc * HO + (size_t)(3 * RG) * m) * WO;
#pragma unroll
    for (int d = 0; d < 3 * RG; ++d) {
        const int r = d / 3 + d % 3;    // compile-time constant per iter
        fvec4 v4;
#pragma unroll
        for (int e = 0; e < 4; ++e) {
            const int t = tcol[e];
            v4[e] = ((unsigned)t < (unsigned)W_N) ? rows[r][t] : 0.f;
        }
        __builtin_nontemporal_store(
            v4, reinterpret_cast<fvec4*>(out + obase + (size_t)d * WO) + tid);
    }
}

extern "C" void kernel_launch(void* const* d_in, const int* in_sizes, int n_in,
                              void* d_out, int out_size, void* d_ws, size_t ws_size,
                              hipStream_t stream)
{
    const float* x = (const float*)d_in[0];
    float* out = (float*)d_out;

    dim3 grid(H_N / RG, B_N * C_N);   // (64, 24) blocks
    dim3 block(WO / 4);               // 384 threads
    unfold_tile_kernel<<<grid, block, 0, stream>>>(x, out);
}

// Round 6
// 41.555 us; speedup vs baseline: 1.1925x; 1.1925x over previous
//
#include <hip/hip_runtime.h>

// Unfolder: out[b,c,p,q] = x[b,c, p/3 + p%3 - 1, q/3 + q%3 - 1], zero outside.
// B=8, C=3, H=W=512, k=3, pad=1 -> out is [8,3,1536,1536] fp32.
//
// R6 experiment: write-stream locality. Linear block id over the output,
// XCD-chunked bijective swizzle (each XCD writes one contiguous ~28 MB
// region), NORMAL stores (through L2, so write-back locality applies).
// Block = 12 output rows (4 row-groups), stages 6 input rows in LDS.

#define B_N 8
#define C_N 3
#define H_N 512
#define W_N 512
#define HO 1536
#define WO 1536
#define RG 4             // row-groups per block -> 12 output rows
#define NR (RG + 2)      // staged input rows
#define NBLK (B_N * C_N * (H_N / RG))   // 3072 blocks, divisible by 8

typedef float fvec4 __attribute__((ext_vector_type(4)));

__global__ __launch_bounds__(384) void unfold_swz_kernel(
    const float* __restrict__ x, float* __restrict__ out)
{
    // XCD-chunked bijective swizzle: xcd = gid%8 gets contiguous g-range.
    const int gid = blockIdx.x;                 // [0, 3072)
    const int g   = (gid & 7) * (NBLK / 8) + (gid >> 3);

    const int bc = g / (H_N / RG);              // image [0,24)
    const int mm = g % (H_N / RG);              // row tile within image [0,128)
    const int tid = threadIdx.x;                // [0,384)

    __shared__ float rows[NR][W_N];

    // Stage NR=6 input rows (s = 4mm-1 .. 4mm+4): 768 float4, 2 per thread.
    const int s0 = RG * mm - 1;
#pragma unroll
    for (int it = 0; it < 2; ++it) {
        const int idx = tid + it * 384;
        const int r  = idx >> 7;
        const int cc = idx & 127;
        const int s  = s0 + r;
        fvec4 v = (fvec4)0.f;
        if ((unsigned)s < (unsigned)H_N) {
            v = reinterpret_cast<const fvec4*>(
                    x + ((size_t)bc * H_N + s) * W_N)[cc];
        }
        reinterpret_cast<fvec4*>(&rows[r][0])[cc] = v;
    }
    __syncthreads();

    // Column gather: q = 4*tid + e, t = q/3 + q%3 - 1 in [-1,512].
    int tcol[4];
#pragma unroll
    for (int e = 0; e < 4; ++e) {
        const int q = tid * 4 + e;
        tcol[e] = q / 3 + q % 3 - 1;
    }

    // 12 output rows; row d uses staged row r = d/3 + d%3.
    const size_t obase = ((size_t)bc * HO + (size_t)(3 * RG) * mm) * WO;
#pragma unroll
    for (int d = 0; d < 3 * RG; ++d) {
        const int r = d / 3 + d % 3;
        fvec4 v4;
#pragma unroll
        for (int e = 0; e < 4; ++e) {
            const int t = tcol[e];
            v4[e] = ((unsigned)t < (unsigned)W_N) ? rows[r][t] : 0.f;
        }
        reinterpret_cast<fvec4*>(out + obase + (size_t)d * WO)[tid] = v4;
    }
}

extern "C" void kernel_launch(void* const* d_in, const int* in_sizes, int n_in,
                              void* d_out, int out_size, void* d_ws, size_t ws_size,
                              hipStream_t stream)
{
    const float* x = (const float*)d_in[0];
    float* out = (float*)d_out;

    dim3 grid(NBLK);      // 3072 linear blocks, XCD-swizzled in-kernel
    dim3 block(WO / 4);   // 384 threads
    unfold_swz_kernel<<<grid, block, 0, stream>>>(x, out);
}